// Round 3
// baseline (181.584 us; speedup 1.0000x reference)
//
#include <hip/hip_runtime.h>

// h_t = a*h_{t-1} + b*x_t + c, h_{-1}=0; z = w*h_{T-1} + e
//
// Closed form: h_{T-1} = b * sum_t a^{T-1-t} x_t  +  c * (1-a^T)/(1-a).
// a in [0.95, 0.999] => neglected tail beyond K offsets is bounded by
// a^K * 100; K = 32768 gives ~6e-13 -- invisible in fp32. So we read only
// the last 128 KB of the 128 MB input, in ONE dispatch (single 1024-thread
// workgroup; no workspace, no second launch). Timed duration is dominated
// by the harness's ~156 us d_ws poison fills, so minimizing dispatch count
// is the only remaining lever.

#define TAIL_K 32768
#define BLOCK  1024

__global__ __launch_bounds__(BLOCK) void fused_scan_tail(
    const float* __restrict__ x,
    const float* __restrict__ a_p, const float* __restrict__ b_p,
    const float* __restrict__ c_p, const float* __restrict__ w_p,
    const float* __restrict__ e_p,
    long long T, int K, float* __restrict__ out)
{
    const int t = threadIdx.x;
    const double a = (double)a_p[0];

    // weight for offset-from-end o is a^o; thread t handles o = t, t+BLOCK, ...
    double wgt        = pow(a, (double)t);
    const double mult = pow(a, (double)BLOCK);
    double acc = 0.0;

    for (int o = t; o < K; o += BLOCK) {
        acc += wgt * (double)x[T - 1 - o];     // descending, coalesced per wave
        wgt *= mult;
    }

    __shared__ double sdata[BLOCK];
    sdata[t] = acc;
    __syncthreads();
    #pragma unroll
    for (int off = BLOCK / 2; off > 0; off >>= 1) {
        if (t < off) sdata[t] += sdata[t + off];
        __syncthreads();
    }

    if (t == 0) {
        const double b = (double)b_p[0];
        const double c = (double)c_p[0];
        const double w = (double)w_p[0];
        const double e = (double)e_p[0];
        const double aT = pow(a, (double)T);   // underflows to 0 for T=2^25
        const double G  = (1.0 - aT) / (1.0 - a);
        const double h  = b * sdata[0] + c * G;
        out[0] = (float)(w * h + e);
    }
}

extern "C" void kernel_launch(void* const* d_in, const int* in_sizes, int n_in,
                              void* d_out, int out_size, void* d_ws, size_t ws_size,
                              hipStream_t stream)
{
    const float* x = (const float*)d_in[0];
    const float* a = (const float*)d_in[1];
    const float* b = (const float*)d_in[2];
    const float* c = (const float*)d_in[3];
    const float* w = (const float*)d_in[4];
    const float* e = (const float*)d_in[5];
    float* out = (float*)d_out;

    const long long T = (long long)in_sizes[0];
    int K = TAIL_K;
    if ((long long)K > T) K = (int)T;

    fused_scan_tail<<<1, BLOCK, 0, stream>>>(x, a, b, c, w, e, T, K, out);
}

// Round 7
// 171.443 us; speedup vs baseline: 1.0592x; 1.0592x over previous
//
#include <hip/hip_runtime.h>

// h_t = a*h_{t-1} + b*x_t + c, h_{-1}=0; z = w*h_{T-1} + e
//
// Closed form: h_{T-1} = b * sum_t a^{T-1-t} x_t  +  c * (1-a^T)/(1-a).
// a in [0.95, 0.999] => tail beyond K=32768 offsets bounded by a^K*100
// ~ 6e-13 -- invisible in fp32. Read only the last 128 KB of the input.
//
// Round-3 lesson: a single 1-block kernel serializes the read + pow on one
// CU (latency-bound, ~+13us). Multi-CU 2-dispatch (Round-1 structure) was
// measurably faster; this round keeps that structure with the smaller K
// and fewer blocks. Timed duration is dominated by harness poison fills
// (~78.5us each, 85% HBM peak) which are outside kernel control.

#define TAIL_K   32768
#define NBLOCKS  32
#define BLOCK    256

__global__ __launch_bounds__(BLOCK) void tail_weighted_sum(
    const float* __restrict__ x,
    const float* __restrict__ a_p,
    long long T, int K,
    double* __restrict__ partials)
{
    const int NT = NBLOCKS * BLOCK;                    // 8192 threads
    const int g  = blockIdx.x * BLOCK + threadIdx.x;
    const double a = (double)a_p[0];

    // offset-from-end o has weight a^o; thread g handles o = g, g+NT, ...
    double wgt        = pow(a, (double)g);
    const double mult = pow(a, (double)NT);
    double acc = 0.0;

    for (int o = g; o < K; o += NT) {                  // 4 iterations
        acc += wgt * (double)x[T - 1 - o];             // coalesced (reversed)
        wgt *= mult;
    }

    // wave reduce (64 lanes), then LDS across the 4 waves
    #pragma unroll
    for (int off = 32; off > 0; off >>= 1)
        acc += __shfl_down(acc, off, 64);

    __shared__ double wsum[BLOCK / 64];
    const int wave = threadIdx.x >> 6;
    if ((threadIdx.x & 63) == 0) wsum[wave] = acc;
    __syncthreads();
    if (threadIdx.x == 0)
        partials[blockIdx.x] = wsum[0] + wsum[1] + wsum[2] + wsum[3];
}

__global__ void finalize(
    const double* __restrict__ partials, int nparts,
    const float* __restrict__ a_p, const float* __restrict__ b_p,
    const float* __restrict__ c_p, const float* __restrict__ w_p,
    const float* __restrict__ e_p,
    long long T, float* __restrict__ out)
{
    const int lane = threadIdx.x;                      // one wave of 64
    double s = (lane < nparts) ? partials[lane] : 0.0;
    #pragma unroll
    for (int off = 32; off > 0; off >>= 1)
        s += __shfl_down(s, off, 64);

    if (lane == 0) {
        const double a = (double)a_p[0];
        const double b = (double)b_p[0];
        const double c = (double)c_p[0];
        const double w = (double)w_p[0];
        const double e = (double)e_p[0];
        const double aT = pow(a, (double)T);           // underflows to 0
        const double G  = (1.0 - aT) / (1.0 - a);
        const double h  = b * s + c * G;
        out[0] = (float)(w * h + e);
    }
}

extern "C" void kernel_launch(void* const* d_in, const int* in_sizes, int n_in,
                              void* d_out, int out_size, void* d_ws, size_t ws_size,
                              hipStream_t stream)
{
    const float* x = (const float*)d_in[0];
    const float* a = (const float*)d_in[1];
    const float* b = (const float*)d_in[2];
    const float* c = (const float*)d_in[3];
    const float* w = (const float*)d_in[4];
    const float* e = (const float*)d_in[5];
    float* out = (float*)d_out;

    const long long T = (long long)in_sizes[0];
    int K = TAIL_K;
    if ((long long)K > T) K = (int)T;

    double* partials = (double*)d_ws;                  // 32 * 8 B

    tail_weighted_sum<<<NBLOCKS, BLOCK, 0, stream>>>(x, a, T, K, partials);
    finalize<<<1, 64, 0, stream>>>(partials, NBLOCKS, a, b, c, w, e, T, out);
}